// Round 10
// baseline (603.817 us; speedup 1.0000x reference)
//
#include <hip/hip_runtime.h>
#include <hip/hip_fp16.h>
#include <math.h>

#define B_SZ 64
#define T_SZ 512
#define M_TOT (B_SZ * T_SZ)   // 32768 tokens
#define HSTR  160             // uints per weight row (320 halves; rows/cols >=300 zero)
#define NPASS 11              // fixed-point refinement passes (halo 16 >= NPASS)
#define BROW  328             // halves per LDS G row: 656B = 41*16 -> b128 reads ALIGNED
#define BUF1  (81 * BROW)     // element offset of second G buffer
#define NEGB  -60000.0f       // pad-bias poison: relu->0, sigm->0

typedef _Float16 f16x8 __attribute__((ext_vector_type(8)));
typedef float    f32x4 __attribute__((ext_vector_type(4)));

__device__ __forceinline__ unsigned int packrte(float a, float b) {
    __half2 h = __floats2half2_rn(a, b);
    return __builtin_bit_cast(unsigned int, h);
}
// rcp-based sigmoid (validated r6-r9: absmax bit-identical, VALU halved).
__device__ __forceinline__ float sigm(float v) {
    return __builtin_amdgcn_rcpf(1.f + __expf(-v));
}

// =====================================================================
// Weights fp32 -> packed f16x2, zero-padded to 320x320.  m=4: padded
// bias vectors (pads poisoned with NEGB so relu/sigm give exact 0).
// =====================================================================
__global__ __launch_bounds__(160) void wconv(
    const float* __restrict__ fc1_w, const float* __restrict__ l1_w,
    const float* __restrict__ l2_w, const float* __restrict__ fc1_b,
    const float* __restrict__ l1_b, const float* __restrict__ l2_b,
    unsigned int* __restrict__ Wh, float* __restrict__ BP)
{
    const int r = blockIdx.x, m = blockIdx.y, j = threadIdx.x;
    if (m == 4) {
        if (j == 0) BP[r]       = (r < 300) ? fc1_b[r] : NEGB;
        if (j == 1) BP[320 + r] = (r < 300) ? l1_b[r]  : NEGB;
        if (j == 2) BP[640 + r] = (r < 300) ? l2_b[r]  : 0.f;
        return;
    }
    const float* src; int stride, off;
    if (m == 0)      { src = fc1_w; stride = 300; off = 0; }
    else if (m == 1) { src = l1_w;  stride = 600; off = 0; }
    else if (m == 2) { src = l2_w;  stride = 300; off = 0; }
    else             { src = l1_w;  stride = 600; off = 300; }
    int k = 2 * j;
    bool rv = (r < 300);
    float a = (rv && k     < 300) ? src[(long)r * stride + off + k]     : 0.f;
    float b = (rv && k + 1 < 300) ? src[(long)r * stride + off + k + 1] : 0.f;
    Wh[((long)m * 320 + r) * HSTR + j] = packrte(a, b);
}

// =====================================================================
// Fused per-64-row-tile kernel: 10 waves (640 thr), ping-pong G buffers
// with compile-time offsets (one barrier/pass).  Wave decomposition:
// 5 col-groups (cg, 64 cols, nt=4) x 2 row-groups (rg0: mt 0-2,
// rg1: mt 3-4).  Each ds_read_b128 G-fragment feeds 4 MFMAs -> 250
// reads/pass/block (was 500 at nt=2).  No explicit LDS-fragment
// double-buffer (r9's bc_/bn_ 80-reg spill source): bg_ read inline,
// compiler pipelines with freed registers.  Weights 1-kc-ahead.
// Swapped MFMA: D col(ml)=token, row(q*4+r)=out col -> packed b64 writes.
// =====================================================================
__global__ __launch_bounds__(640, 3) void rnn_mega(
    const int* __restrict__ x, const float* __restrict__ emb,
    const float* __restrict__ BP, const unsigned int* __restrict__ Wh,
    float* __restrict__ part)
{
    __shared__ _Float16 Gt[2 * 81 * BROW];   // row 0 of each buf = zero row
    __shared__ float red2[320];              // cross-rg epilogue max

    const int tid  = threadIdx.x;
    const int lane = tid & 63;
    const int ml   = lane & 15;
    const int q    = lane >> 4;
    const int ww   = tid >> 6;           // 0..9
    const int cg   = ww >> 1;            // col-group 0..4
    const int rg   = ww & 1;             // row-group: 0 -> mt 0-2, 1 -> mt 3-4
    const int c0   = cg * 64;            // wave's 64 output cols
    const int m0   = blockIdx.x * 64;
    const int m0h  = m0 - 16;
    const bool bstart = (m0 & (T_SZ - 1)) == 0;
    const unsigned int killm = (bstart && ml == 15) ? 0u : ~0u;  // row t=m0-1

    const uint4* Wq = (const uint4*)Wh;             // 40 uint4 per row
    const float* bpf  = BP;
    const float* bpl1 = BP + 320;
    const float* bpl2 = BP + 640;

    // per-wave LDS bases; buffer select = +0 / +BUF1 compile-time offset
    const _Float16* grd = &Gt[ml * BROW + q * 8];             // B-frag reads
    _Float16*       gwr = &Gt[(ml + 1) * BROW + c0 + q * 4];  // update writes

    // ---- stage emb[x[m0h..m0h+80)] as f16 into buf0 rows 1..80
    #pragma unroll
    for (int it = 0; it < 5; ++it) {
        int li  = it * 640 + tid;      // 0..3199
        int row = li / 40;             // 0..79
        int sg  = li % 40;             // 8-half segment
        int g   = m0h + row; if (g < 0) g = 0;   // block 0 halo clamp
        const float* er = emb + (long)x[g] * 300;
        int k = sg * 8;
        float4 f0 = (k + 4 <= 300) ? *(const float4*)(er + k)     : make_float4(0,0,0,0);
        float4 f1 = (k + 8 <= 300) ? *(const float4*)(er + k + 4) : make_float4(0,0,0,0);
        *(uint4*)&Gt[(row + 1) * BROW + sg * 8] =
            make_uint4(packrte(f0.x, f0.y), packrte(f0.z, f0.w),
                       packrte(f1.x, f1.y), packrte(f1.z, f1.w));
    }
    if (tid < 41) {                    // zero row 0 of both buffers
        *(uint4*)&Gt[tid * 8]        = make_uint4(0, 0, 0, 0);
        *(uint4*)&Gt[BUF1 + tid * 8] = make_uint4(0, 0, 0, 0);
    }
    __syncthreads();

    f32x4        acc[3][4];            // rg0 uses [0..2], rg1 [0..1]
    unsigned int xpk[3][4][2];

    // GEMM over wave's mt range: acc[li][nt], li = mt - MTA.
    // Weights 1-kc-ahead from L2; bg_ read inline (compiler pipelines).
    #define RUN_GEMM_P(WQ, RO, MTA, LI0, NMT, BOFF) do {                      \
        _Pragma("unroll") for (int li = (LI0); li < (NMT); ++li)              \
        _Pragma("unroll") for (int nt = 0; nt < 4; ++nt)                      \
            acc[li][nt] = (f32x4){0.f, 0.f, 0.f, 0.f};                        \
        const uint4* wp_ = (WQ) + (c0 + ml) * 40 + q;                         \
        uint4 a_[4], an_[4];                                                  \
        _Pragma("unroll") for (int nt = 0; nt < 4; ++nt)                      \
            a_[nt] = wp_[nt * 640];                                           \
        _Pragma("unroll") for (int kc = 0; kc < 10; ++kc) {                   \
            if (kc < 9) {                                                     \
                _Pragma("unroll") for (int nt = 0; nt < 4; ++nt)              \
                    an_[nt] = wp_[nt * 640 + (kc + 1) * 4];                   \
            }                                                                 \
            _Pragma("unroll") for (int li = (LI0); li < (NMT); ++li) {        \
                f16x8 bg_ = *(const f16x8*)(grd + (BOFF)                      \
                            + (((MTA) + li) * 16 + (RO)) * BROW + kc * 32);   \
                _Pragma("unroll") for (int nt = 0; nt < 4; ++nt)              \
                    acc[li][nt] = __builtin_amdgcn_mfma_f32_16x16x32_f16(     \
                        __builtin_bit_cast(f16x8, a_[nt]), bg_, acc[li][nt],  \
                        0, 0, 0);                                             \
            }                                                                 \
            _Pragma("unroll") for (int nt = 0; nt < 4; ++nt)                  \
                a_[nt] = an_[nt];                                             \
        } } while (0)

    // sigmoid update into buffer BOFF
    #define UPDATE_G_P(MTA, LI0, NMT, BOFF) do {                              \
        _Pragma("unroll") for (int li = (LI0); li < (NMT); ++li)              \
        _Pragma("unroll") for (int nt = 0; nt < 4; ++nt) {                    \
            __half2 plo = __builtin_bit_cast(__half2, xpk[li][nt][0]);        \
            __half2 phi = __builtin_bit_cast(__half2, xpk[li][nt][1]);        \
            float v0 = sigm(acc[li][nt][0] + __low2float(plo));               \
            float v1 = sigm(acc[li][nt][1] + __high2float(plo));              \
            float v2 = sigm(acc[li][nt][2] + __low2float(phi));               \
            float v3 = sigm(acc[li][nt][3] + __high2float(phi));              \
            unsigned int p0 = packrte(v0, v1), p1 = packrte(v2, v3);          \
            if ((MTA) + li == 0) { p0 &= killm; p1 &= killm; }                \
            *(uint2*)(gwr + (BOFF) + ((MTA) + li) * 16 * BROW + nt * 16) =    \
                make_uint2(p0, p1);                                           \
        } } while (0)

    // relu+bias h-store into buf1
    #define HSTORE_P(MTA, NMT) do {                                           \
        _Pragma("unroll") for (int nt = 0; nt < 4; ++nt) {                    \
            float4 bb = *(const float4*)(bpf + c0 + nt * 16 + q * 4);         \
            _Pragma("unroll") for (int li = 0; li < (NMT); ++li) {            \
                float v0 = fmaxf(acc[li][nt][0] + bb.x, 0.f);                 \
                float v1 = fmaxf(acc[li][nt][1] + bb.y, 0.f);                 \
                float v2 = fmaxf(acc[li][nt][2] + bb.z, 0.f);                 \
                float v3 = fmaxf(acc[li][nt][3] + bb.w, 0.f);                 \
                *(uint2*)(gwr + BUF1 + ((MTA) + li) * 16 * BROW + nt * 16) =  \
                    make_uint2(packrte(v0, v1), packrte(v2, v3));             \
            } } } while (0)

    // xp = acc + l1 bias -> packed f16 regs
    #define XPSAVE_P(NMT) do {                                                \
        _Pragma("unroll") for (int nt = 0; nt < 4; ++nt) {                    \
            float4 bb = *(const float4*)(bpl1 + c0 + nt * 16 + q * 4);        \
            _Pragma("unroll") for (int li = 0; li < (NMT); ++li) {            \
                xpk[li][nt][0] = packrte(acc[li][nt][0] + bb.x,               \
                                         acc[li][nt][1] + bb.y);              \
                xpk[li][nt][1] = packrte(acc[li][nt][2] + bb.z,               \
                                         acc[li][nt][3] + bb.w);              \
            } } } while (0)

    // G^0 = sigm(xp) into buf0
    #define GINIT_P(MTA, NMT) do {                                            \
        _Pragma("unroll") for (int li = 0; li < (NMT); ++li)                  \
        _Pragma("unroll") for (int nt = 0; nt < 4; ++nt) {                    \
            __half2 plo = __builtin_bit_cast(__half2, xpk[li][nt][0]);        \
            __half2 phi = __builtin_bit_cast(__half2, xpk[li][nt][1]);        \
            unsigned int p0 = packrte(sigm(__low2float(plo)),                 \
                                      sigm(__high2float(plo)));               \
            unsigned int p1 = packrte(sigm(__low2float(phi)),                 \
                                      sigm(__high2float(phi)));               \
            if ((MTA) + li == 0) { p0 &= killm; p1 &= killm; }                \
            *(uint2*)(gwr + ((MTA) + li) * 16 * BROW + nt * 16) =             \
                make_uint2(p0, p1);                                           \
        } } while (0)

    // ---- h = relu(embf16 @ fc1.T + fc1_b): read buf0 (emb), write buf1
    if (rg == 0) { RUN_GEMM_P(Wq, 1, 0, 0, 3, 0);  HSTORE_P(0, 3); }
    else         { RUN_GEMM_P(Wq, 1, 3, 0, 2, 0);  HSTORE_P(3, 2); }
    __syncthreads();                  // h (buf1) visible

    // ---- xp = h @ l1_wx.T + l1_b (read buf1); G^0 = sigm(xp) -> buf0
    if (rg == 0) { RUN_GEMM_P(Wq + 320 * 40, 1, 0, 0, 3, BUF1);
                   XPSAVE_P(3);  GINIT_P(0, 3); }
    else         { RUN_GEMM_P(Wq + 320 * 40, 1, 3, 0, 2, BUF1);
                   XPSAVE_P(2);  GINIT_P(3, 2); }
    __syncthreads();                  // G^0 (buf0) visible

    // ---- 10 fixed-point passes in ping-pong pairs, one barrier/pass
    #pragma unroll 1
    for (int pp = 0; pp < (NPASS - 1) / 2; ++pp) {
        if (rg == 0) { RUN_GEMM_P(Wq + 3 * 320 * 40, 0, 0, 0, 3, 0);
                       UPDATE_G_P(0, 0, 3, BUF1); }
        else         { RUN_GEMM_P(Wq + 3 * 320 * 40, 0, 3, 0, 2, 0);
                       UPDATE_G_P(3, 0, 2, BUF1); }
        __syncthreads();
        if (rg == 0) { RUN_GEMM_P(Wq + 3 * 320 * 40, 0, 0, 0, 3, BUF1);
                       UPDATE_G_P(0, 0, 3, 0); }
        else         { RUN_GEMM_P(Wq + 3 * 320 * 40, 0, 3, 0, 2, BUF1);
                       UPDATE_G_P(3, 0, 2, 0); }
        __syncthreads();
    }
    // pass 10 (last; halo rows mt0 dead): read buf0 -> write buf1
    if (rg == 0) { RUN_GEMM_P(Wq + 3 * 320 * 40, 0, 0, 1, 3, 0);
                   UPDATE_G_P(0, 1, 3, BUF1); }
    else         { RUN_GEMM_P(Wq + 3 * 320 * 40, 0, 3, 0, 2, 0);
                   UPDATE_G_P(3, 0, 2, BUF1); }
    __syncthreads();

    // ---- out = G @ l2.T over output tokens (final G in buf1);
    //      per-wave max over its rows, cross-rg combine via red2
    float vout[4][4];
    if (rg == 1) {
        RUN_GEMM_P(Wq + 2 * 320 * 40, 1, 3, 0, 2, BUF1);
        #pragma unroll
        for (int nt = 0; nt < 4; ++nt)
        #pragma unroll
        for (int r = 0; r < 4; ++r) {
            float v = fmaxf(acc[0][nt][r], acc[1][nt][r]);
            v = fmaxf(v, __shfl_xor(v, 1));
            v = fmaxf(v, __shfl_xor(v, 2));
            v = fmaxf(v, __shfl_xor(v, 4));
            v = fmaxf(v, __shfl_xor(v, 8));
            if (ml == 0) red2[c0 + nt * 16 + q * 4 + r] = v;
        }
    } else {
        RUN_GEMM_P(Wq + 2 * 320 * 40, 1, 0, 1, 3, BUF1);
        #pragma unroll
        for (int nt = 0; nt < 4; ++nt)
        #pragma unroll
        for (int r = 0; r < 4; ++r) {
            float v = fmaxf(acc[1][nt][r], acc[2][nt][r]);
            v = fmaxf(v, __shfl_xor(v, 1));
            v = fmaxf(v, __shfl_xor(v, 2));
            v = fmaxf(v, __shfl_xor(v, 4));
            v = fmaxf(v, __shfl_xor(v, 8));
            vout[nt][r] = v;
        }
    }
    __syncthreads();
    if (rg == 0 && ml == 0) {
        #pragma unroll
        for (int nt = 0; nt < 4; ++nt)
        #pragma unroll
        for (int r = 0; r < 4; ++r) {
            int col = c0 + nt * 16 + q * 4 + r;
            part[(long)blockIdx.x * 320 + col] =
                fmaxf(vout[nt][r], red2[col]) + bpl2[col];
        }
    }
    #undef RUN_GEMM_P
    #undef UPDATE_G_P
    #undef HSTORE_P
    #undef XPSAVE_P
    #undef GINIT_P
}

// =====================================================================
// Final: pooled[b,n] = max over 8 m-chunks of part; out = pooled @ fc2_w.T
// =====================================================================
__global__ __launch_bounds__(320) void fc2_final(
    const float* __restrict__ part,     // [512, 320]
    const float* __restrict__ fc2_w,
    const float* __restrict__ fc2_b,
    float* __restrict__ out)
{
    const int b   = blockIdx.x;
    const int tid = threadIdx.x;
    __shared__ float pooled[304];

    if (tid < 300) {
        float m = part[(long)(b * 8) * 320 + tid];
        #pragma unroll
        for (int c = 1; c < 8; c++)
            m = fmaxf(m, part[(long)(b * 8 + c) * 320 + tid]);
        pooled[tid] = m;
    }
    __syncthreads();

    const int o    = tid >> 6;
    const int lane = tid & 63;
    if (o < 2) {
        float sacc = 0.f;
        for (int jj = lane; jj < 300; jj += 64)
            sacc += pooled[jj] * fc2_w[o * 300 + jj];
        #pragma unroll
        for (int off = 32; off > 0; off >>= 1)
            sacc += __shfl_down(sacc, off);
        if (lane == 0) out[b * 2 + o] = sacc + fc2_b[o];
    }
}

// =====================================================================
extern "C" void kernel_launch(void* const* d_in, const int* in_sizes, int n_in,
                              void* d_out, int out_size, void* d_ws, size_t ws_size,
                              hipStream_t stream)
{
    const int*   x     = (const int*)  d_in[0];
    const float* emb   = (const float*)d_in[1];
    const float* fc1_w = (const float*)d_in[2];
    const float* fc1_b = (const float*)d_in[3];
    const float* l1_w  = (const float*)d_in[4];
    const float* l1_b  = (const float*)d_in[5];
    const float* l2_w  = (const float*)d_in[6];
    const float* l2_b  = (const float*)d_in[7];
    const float* fc2_w = (const float*)d_in[8];
    const float* fc2_b = (const float*)d_in[9];
    float* out = (float*)d_out;

    // ws: part [512*320 f32] | Wh [4*320*160 uints] | BP [960 f32]
    float* part = (float*)d_ws;
    unsigned int* Wh = (unsigned int*)(part + (size_t)512 * 320);
    float* BP = (float*)(Wh + (size_t)4 * 320 * HSTR);

    wconv<<<dim3(320, 5), 160, 0, stream>>>(
        fc1_w, l1_w, l2_w, fc1_b, l1_b, l2_b, Wh, BP);
    rnn_mega<<<M_TOT / 64, 640, 0, stream>>>(x, emb, BP, Wh, part);
    fc2_final<<<B_SZ, 320, 0, stream>>>(part, fc2_w, fc2_b, out);
}